// Round 4
// baseline (13459.955 us; speedup 1.0000x reference)
//
#include <hip/hip_runtime.h>
#include <math.h>

// L=1024, B=24, D=512.
// Pipeline: tk=tanh(v.Wp_^T) [full]; per 128-i chunk: tq, fused
// scores+softmax+context (attn), Gi = C.w_ih^T+b_ih, then a persistent GRU
// kernel doing 128 steps with tagged-word handshakes.
// R5-R7 post-mortem: VGPR_Count (120/128/124/52) proved the compiler NEVER
// keeps the weight fragment register-resident, regardless of size (192 or 48
// floats) or launch_bounds. Weights streamed from L2 every segment:
// ~196KB/CU/segment at ~145 GB/s/CU = the invariant ~1.4us/segment floor all
// four rounds shared. Body/barrier/handshake tweaks were noise on top.
// R8 (this round): weights go to LDS (deterministic residency) and the 3
// batches of a group are FUSED per step so one 98KB LDS weight read serves
// all 3 (amortization beats the stagger's latency hiding: exposed cost is
// one publish->visible hop ~0.35us/il vs 2 extra weight passes ~2.8us).
// Grid 256 = 32 slices x 8 groups, 1024 thr, 16 rows/block.
// wave = row, lane = 8-wide k-chunk; skew k+((k>>5)<<2) makes w/h
// ds_read_b128 conflict-free (each 8-lane group tiles all 32 banks once).
// 6-step shfl_xor butterfly; lanes 0-2 do gates+publish for batches 0-2.

// ---------------------------------------------------------------------------
// GEMM: out[m][n] = post(A[m][:] . B[n][:] (+ bias[n])), A: MxK rm, B: NxK rm.
__launch_bounds__(256, 2)
__global__ void gemm_abt_kernel(const float* __restrict__ A, const float* __restrict__ B,
                                float* __restrict__ out, int K, int N,
                                const float* __restrict__ bias, int do_tanh) {
  __shared__ __align__(16) float As[16][136];
  __shared__ __align__(16) float Bs[16][136];
  const int m0 = blockIdx.y * 128, n0 = blockIdx.x * 128;
  const int tid = threadIdx.x;
  const int tm = (tid & 15) * 8, tn = (tid >> 4) * 8;
  const int srow = tid & 127, scol = (tid >> 7) * 8;
  const float* Ap = A + (size_t)(m0 + srow) * K + scol;
  const float* Bp = B + (size_t)(n0 + srow) * K + scol;
  float acc[8][8] = {{0.f}};
  for (int k0 = 0; k0 < K; k0 += 16) {
    const float4 a0 = *(const float4*)(Ap + k0);
    const float4 a1 = *(const float4*)(Ap + k0 + 4);
    const float4 b0 = *(const float4*)(Bp + k0);
    const float4 b1 = *(const float4*)(Bp + k0 + 4);
    __syncthreads();
    As[scol + 0][srow] = a0.x; As[scol + 1][srow] = a0.y;
    As[scol + 2][srow] = a0.z; As[scol + 3][srow] = a0.w;
    As[scol + 4][srow] = a1.x; As[scol + 5][srow] = a1.y;
    As[scol + 6][srow] = a1.z; As[scol + 7][srow] = a1.w;
    Bs[scol + 0][srow] = b0.x; Bs[scol + 1][srow] = b0.y;
    Bs[scol + 2][srow] = b0.z; Bs[scol + 3][srow] = b0.w;
    Bs[scol + 4][srow] = b1.x; Bs[scol + 5][srow] = b1.y;
    Bs[scol + 6][srow] = b1.z; Bs[scol + 7][srow] = b1.w;
    __syncthreads();
#pragma unroll
    for (int kk = 0; kk < 16; ++kk) {
      const float4 av0 = *(const float4*)&As[kk][tm];
      const float4 av1 = *(const float4*)&As[kk][tm + 4];
      const float4 bv0 = *(const float4*)&Bs[kk][tn];
      const float4 bv1 = *(const float4*)&Bs[kk][tn + 4];
      const float ar[8] = {av0.x, av0.y, av0.z, av0.w, av1.x, av1.y, av1.z, av1.w};
      const float br[8] = {bv0.x, bv0.y, bv0.z, bv0.w, bv1.x, bv1.y, bv1.z, bv1.w};
#pragma unroll
      for (int r = 0; r < 8; ++r)
#pragma unroll
        for (int c = 0; c < 8; ++c)
          acc[r][c] = fmaf(ar[r], br[c], acc[r][c]);
    }
  }
#pragma unroll
  for (int r = 0; r < 8; ++r) {
    float* o = out + (size_t)(m0 + tm + r) * N + n0 + tn;
#pragma unroll
    for (int c = 0; c < 8; ++c) {
      float val = acc[r][c];
      if (bias) val += bias[n0 + tn + c];
      if (do_tanh) val = tanhf(val);
      o[c] = val;
    }
  }
}

// ---------------------------------------------------------------------------
// Fused scores + softmax + context for one i-chunk.
// tanh(q+k) = u + w(1-u^2)/(1+uw); sum_h V*u is const in l -> dropped
// (softmax-invariant). V'[i][h] = V[h]*(1-u^2) lives in registers.
__launch_bounds__(256, 3)
__global__ void attn_kernel(const float* __restrict__ tq, const float* __restrict__ tk,
                            const float* __restrict__ Vv, const float* __restrict__ v,
                            float* __restrict__ Cout) {
  const int b = blockIdx.y;
  const int it = blockIdx.x;           // i-tile within chunk (il = it*4+ii)
  const int tid = threadIdx.x;
  const int wave = tid >> 6, lane = tid & 63;
  const int h8 = lane * 8;
  __shared__ __align__(16) float sm[4][1024];
  __shared__ __align__(16) float red[4][4][512];
  __shared__ float inv_s[4];

  float q[4][8], vp[4][8];
  {
    const float* vvp = Vv + (size_t)b * 512 + h8;
    const float4 v0 = *(const float4*)vvp;
    const float4 v1 = *(const float4*)(vvp + 4);
    const float vv[8] = {v0.x, v0.y, v0.z, v0.w, v1.x, v1.y, v1.z, v1.w};
#pragma unroll
    for (int ii = 0; ii < 4; ++ii) {
      const float* qp = tq + ((size_t)(it * 4 + ii) * 24 + b) * 512 + h8;
      const float4 q0 = *(const float4*)qp;
      const float4 q1 = *(const float4*)(qp + 4);
      q[ii][0] = q0.x; q[ii][1] = q0.y; q[ii][2] = q0.z; q[ii][3] = q0.w;
      q[ii][4] = q1.x; q[ii][5] = q1.y; q[ii][6] = q1.z; q[ii][7] = q1.w;
#pragma unroll
      for (int j = 0; j < 8; ++j)
        vp[ii][j] = vv[j] * (1.0f - q[ii][j] * q[ii][j]);
    }
  }

  for (int l = wave; l < 1024; l += 4) {
    const float* kp = tk + ((size_t)l * 24 + b) * 512 + h8;
    const float4 k0 = *(const float4*)kp;
    const float4 k1 = *(const float4*)(kp + 4);
    const float kkv[8] = {k0.x, k0.y, k0.z, k0.w, k1.x, k1.y, k1.z, k1.w};
    float acc0 = 0.f, acc1 = 0.f, acc2 = 0.f, acc3 = 0.f;
#pragma unroll
    for (int j = 0; j < 8; ++j) {
      const float w = kkv[j];
      acc0 = fmaf(vp[0][j] * w, __builtin_amdgcn_rcpf(fmaf(q[0][j], w, 1.0f)), acc0);
      acc1 = fmaf(vp[1][j] * w, __builtin_amdgcn_rcpf(fmaf(q[1][j], w, 1.0f)), acc1);
      acc2 = fmaf(vp[2][j] * w, __builtin_amdgcn_rcpf(fmaf(q[2][j], w, 1.0f)), acc2);
      acc3 = fmaf(vp[3][j] * w, __builtin_amdgcn_rcpf(fmaf(q[3][j], w, 1.0f)), acc3);
    }
#pragma unroll
    for (int mask = 32; mask; mask >>= 1) {
      acc0 += __shfl_xor(acc0, mask, 64);
      acc1 += __shfl_xor(acc1, mask, 64);
      acc2 += __shfl_xor(acc2, mask, 64);
      acc3 += __shfl_xor(acc3, mask, 64);
    }
    if (lane == 0) {
      sm[0][l] = acc0; sm[1][l] = acc1; sm[2][l] = acc2; sm[3][l] = acc3;
    }
  }
  __syncthreads();

  // softmax of row `wave` in place (exp only; normalization folded into output)
  {
    float* row = sm[wave];
    float m = -1e30f;
    for (int t = lane; t < 1024; t += 64) m = fmaxf(m, row[t]);
#pragma unroll
    for (int mask = 32; mask; mask >>= 1) m = fmaxf(m, __shfl_xor(m, mask, 64));
    float s = 0.f;
    for (int t = lane; t < 1024; t += 64) {
      const float e = __expf(row[t] - m);
      row[t] = e;
      s += e;
    }
#pragma unroll
    for (int mask = 32; mask; mask >>= 1) s += __shfl_xor(s, mask, 64);
    if (lane == 0) inv_s[wave] = 1.0f / s;
  }
  __syncthreads();

  // context: wave w covers l in [256w, 256w+256), lane owns d-slice h8
  float ca[4][8] = {{0.f}};
  const int l0 = wave * 256;
  for (int l = l0; l < l0 + 256; ++l) {
    const float* vrow = v + ((size_t)l * 24 + b) * 512 + h8;
    const float4 x0 = *(const float4*)vrow;
    const float4 x1 = *(const float4*)(vrow + 4);
    const float a0 = sm[0][l], a1 = sm[1][l], a2 = sm[2][l], a3 = sm[3][l];
    const float xv[8] = {x0.x, x0.y, x0.z, x0.w, x1.x, x1.y, x1.z, x1.w};
#pragma unroll
    for (int j = 0; j < 8; ++j) {
      ca[0][j] = fmaf(a0, xv[j], ca[0][j]);
      ca[1][j] = fmaf(a1, xv[j], ca[1][j]);
      ca[2][j] = fmaf(a2, xv[j], ca[2][j]);
      ca[3][j] = fmaf(a3, xv[j], ca[3][j]);
    }
  }
#pragma unroll
  for (int ii = 0; ii < 4; ++ii) {
    *(float4*)&red[wave][ii][h8]     = make_float4(ca[ii][0], ca[ii][1], ca[ii][2], ca[ii][3]);
    *(float4*)&red[wave][ii][h8 + 4] = make_float4(ca[ii][4], ca[ii][5], ca[ii][6], ca[ii][7]);
  }
  __syncthreads();
  {
    const int ii = tid >> 6;
    const int d0 = (tid & 63) * 8;
    float4 s0 = *(const float4*)&red[0][ii][d0];
    float4 s1 = *(const float4*)&red[0][ii][d0 + 4];
#pragma unroll
    for (int w = 1; w < 4; ++w) {
      const float4 r0 = *(const float4*)&red[w][ii][d0];
      const float4 r1 = *(const float4*)&red[w][ii][d0 + 4];
      s0.x += r0.x; s0.y += r0.y; s0.z += r0.z; s0.w += r0.w;
      s1.x += r1.x; s1.y += r1.y; s1.z += r1.z; s1.w += r1.w;
    }
    const float inv = inv_s[ii];
    s0.x *= inv; s0.y *= inv; s0.z *= inv; s0.w *= inv;
    s1.x *= inv; s1.y *= inv; s1.z *= inv; s1.w *= inv;
    float* o = Cout + ((size_t)(it * 4 + ii) * 24 + b) * 512 + d0;
    *(float4*)o = s0;
    *(float4*)(o + 4) = s1;
  }
}

// ---------------------------------------------------------------------------
// Persistent GRU, LDS-resident weights, 3 batches fused per step.
// Grid 256 = 32 d-slices x 8 groups. Block: 1024 thr = 16 waves; wave w owns
// output row dgr = sl*16 + w; lane l owns k-chunk [8l, 8l+8).
// h exchange: {float h; u32 tag} 8B relaxed agent atomics; consumer at step
// gs polls tag >= gs+1, producer stores tag gs+2; ping-pong hb0/hb1 by step
// parity. Overwrite-safe by the usual induction (every block reads the full
// h_t of its batches before publishing t+1; slot@t is only overwritten at
// t+2). Sync domain = the 32 slice-blocks of a group; no cross-group deps.
// Skew p(k) = k + ((k>>5)<<2): an 8-lane group's b128 reads tile all 32
// banks exactly once -> conflict-free for both w_lds and h_stage.
union HPack {
  unsigned long long u;
  struct { float f; unsigned tag; } s;
};

__launch_bounds__(1024, 1)
__global__ void gru_persist_kernel(const float* __restrict__ Gi_c,
                                   const float* __restrict__ w_hh,
                                   const float* __restrict__ b_hh,
                                   const float* __restrict__ h0,
                                   unsigned long long* __restrict__ hb0,
                                   unsigned long long* __restrict__ hb1,
                                   float* __restrict__ out, int gstep0) {
  const int g  = blockIdx.x & 7;    // batch group (batches 3g..3g+2)
  const int sl = blockIdx.x >> 3;   // d-slice 0..31 (16 rows each)
  const int t  = threadIdx.x;
  const int w  = t >> 6;            // wave == local output row 0..15
  const int l  = t & 63;            // lane == 8-wide k-chunk
  const int dgr = sl * 16 + w;      // global output row

  __shared__ __align__(16) float w_lds[48][576];      // [g*16+r][p(k)] 108KB
  __shared__ __align__(16) float h_stage[2][3][576];  // [buf][q][p(d)]  14KB

  // ---- stage w_hh slice into LDS (once per launch; ~98KB from L2/L3) ----
  for (int e = t; e < 24576; e += 1024) {
    const int k = e & 511, gr = e >> 9;      // gr = gate*16 + r
    const int gg = gr >> 4, r = gr & 15;
    w_lds[gr][k + ((k >> 5) << 2)] =
        w_hh[(size_t)(gg * 512 + sl * 16 + r) * 512 + k];
  }
  const float bias_r = b_hh[dgr];
  const float bias_z = b_hh[512 + dgr];
  const float bias_n = b_hh[1024 + dgr];

  // ---- launch 0: seed h0 (own rows only) into hb1 with tag 1 ----
  if (gstep0 == 0 && t < 48) {
    const int q = t >> 4, d = t & 15;
    const int bg = g * 3 + q;
    HPack p; p.s.f = h0[(size_t)bg * 512 + sl * 16 + d]; p.s.tag = 1u;
    __hip_atomic_store(hb1 + (size_t)bg * 512 + sl * 16 + d, p.u,
                       __ATOMIC_RELAXED, __HIP_MEMORY_SCOPE_AGENT);
  }

  // poll-word ownership: thread t owns (q0 = t>>9, d0 = t&511); threads
  // t<512 additionally own (q=2, d0).
  const int d0 = t & 511;
  const int q0 = t >> 9;
  const bool two = (t < 512);

  float hq = 0.f;   // own previous-h (lanes 0..2 of each wave)

  for (int il = 0; il < 128; ++il) {
    const int gs = gstep0 + il;
    const unsigned want = (unsigned)(gs + 1);
    const unsigned long long* hbR = (gs & 1) ? hb0 : hb1;
    unsigned long long* hbW = (gs & 1) ? hb1 : hb0;
    const int buf = il & 1;

    // hoist gi loads (lanes 0-2 of each wave; consumed after the reduce)
    float gir = 0.f, giz = 0.f, gin = 0.f;
    if (l < 3) {
      const float* gi = Gi_c + ((size_t)il * 24 + (g * 3 + l)) * 1536 + dgr;
      gir = gi[0]; giz = gi[512]; gin = gi[1024];
    }

    // poll + stage h_t of all 3 batches into h_stage[buf]
    {
      const unsigned long long* s1 = hbR + (size_t)(g * 3 + q0) * 512 + d0;
      const unsigned long long* s2 = hbR + (size_t)(g * 3 + 2) * 512 + d0;
      HPack p1, p2;
      p1.u = __hip_atomic_load(s1, __ATOMIC_RELAXED, __HIP_MEMORY_SCOPE_AGENT);
      p2.u = two ? __hip_atomic_load(s2, __ATOMIC_RELAXED, __HIP_MEMORY_SCOPE_AGENT)
                 : p1.u;
      while (p1.s.tag < want || p2.s.tag < want) {
        __builtin_amdgcn_s_sleep(1);
        if (p1.s.tag < want)
          p1.u = __hip_atomic_load(s1, __ATOMIC_RELAXED, __HIP_MEMORY_SCOPE_AGENT);
        if (p2.s.tag < want)
          p2.u = two ? __hip_atomic_load(s2, __ATOMIC_RELAXED, __HIP_MEMORY_SCOPE_AGENT)
                     : p1.u;
      }
      const int sk = d0 + ((d0 >> 5) << 2);
      h_stage[buf][q0][sk] = p1.s.f;
      if (two) h_stage[buf][2][sk] = p2.s.f;
    }
    __syncthreads();   // the only barrier: h_stage[buf] ready
    if (il == 0 && l < 3) hq = h_stage[buf][l][dgr + ((dgr >> 5) << 2)];

    // 9 dots: 3 gates x 3 batches for row dgr over k in [8l, 8l+8)
    const int base = (l << 3) + ((l >> 2) << 2);
    const float4 wA0 = *(const float4*)&w_lds[w][base];
    const float4 wA1 = *(const float4*)&w_lds[w][base + 4];
    const float4 wB0 = *(const float4*)&w_lds[16 + w][base];
    const float4 wB1 = *(const float4*)&w_lds[16 + w][base + 4];
    const float4 wC0 = *(const float4*)&w_lds[32 + w][base];
    const float4 wC1 = *(const float4*)&w_lds[32 + w][base + 4];
    const float4 hA0 = *(const float4*)&h_stage[buf][0][base];
    const float4 hA1 = *(const float4*)&h_stage[buf][0][base + 4];
    const float4 hB0 = *(const float4*)&h_stage[buf][1][base];
    const float4 hB1 = *(const float4*)&h_stage[buf][1][base + 4];
    const float4 hC0 = *(const float4*)&h_stage[buf][2][base];
    const float4 hC1 = *(const float4*)&h_stage[buf][2][base + 4];

#define DOT8(W0, W1, X0, X1)                                                  \
  fmaf((W1).w, (X1).w, fmaf((W1).z, (X1).z, fmaf((W1).y, (X1).y,              \
  fmaf((W1).x, (X1).x, fmaf((W0).w, (X0).w, fmaf((W0).z, (X0).z,              \
  fmaf((W0).y, (X0).y, (W0).x * (X0).x)))))))

    float sAr = DOT8(wA0, wA1, hA0, hA1);
    float sAz = DOT8(wB0, wB1, hA0, hA1);
    float sAn = DOT8(wC0, wC1, hA0, hA1);
    float sBr = DOT8(wA0, wA1, hB0, hB1);
    float sBz = DOT8(wB0, wB1, hB0, hB1);
    float sBn = DOT8(wC0, wC1, hB0, hB1);
    float sCr = DOT8(wA0, wA1, hC0, hC1);
    float sCz = DOT8(wB0, wB1, hC0, hC1);
    float sCn = DOT8(wC0, wC1, hC0, hC1);
#undef DOT8

    // reduce the 64 k-chunks across the wave (butterfly; DPP/permlane path)
#pragma unroll
    for (int m = 1; m < 64; m <<= 1) {
      sAr += __shfl_xor(sAr, m, 64);
      sAz += __shfl_xor(sAz, m, 64);
      sAn += __shfl_xor(sAn, m, 64);
      sBr += __shfl_xor(sBr, m, 64);
      sBz += __shfl_xor(sBz, m, 64);
      sBn += __shfl_xor(sBn, m, 64);
      sCr += __shfl_xor(sCr, m, 64);
      sCz += __shfl_xor(sCz, m, 64);
      sCn += __shfl_xor(sCn, m, 64);
    }

    if (l < 3) {   // lane q handles batch q of this group
      const int bg = g * 3 + l;
      const float sr = (l == 0) ? sAr : (l == 1) ? sBr : sCr;
      const float sz = (l == 0) ? sAz : (l == 1) ? sBz : sCz;
      const float sn = (l == 0) ? sAn : (l == 1) ? sBn : sCn;
      const float rg = __builtin_amdgcn_rcpf(1.0f + __expf(-(gir + sr + bias_r)));
      const float zg = __builtin_amdgcn_rcpf(1.0f + __expf(-(giz + sz + bias_z)));
      const float nx = gin + rg * (sn + bias_n);
      const float e2 = __expf(-2.0f * fabsf(nx));
      const float tn = __builtin_copysignf((1.0f - e2) * __builtin_amdgcn_rcpf(1.0f + e2), nx);
      const float hn = (1.0f - zg) * tn + zg * hq;
      hq = hn;
      HPack pw; pw.s.f = hn; pw.s.tag = (unsigned)(gs + 2);
      __hip_atomic_store(hbW + (size_t)bg * 512 + dgr, pw.u,
                         __ATOMIC_RELAXED, __HIP_MEMORY_SCOPE_AGENT);
      out[((size_t)gs * 24 + bg) * 512 + dgr] = hn;   // after publish: off chain
    }
    // no trailing barrier: next il stages into h_stage[buf^1] (dbuf), and the
    // WAR vs reads from il-1 is ordered by this il's barrier.
  }
}

// ---------------------------------------------------------------------------
extern "C" void kernel_launch(void* const* d_in, const int* in_sizes, int n_in,
                              void* d_out, int out_size, void* d_ws, size_t ws_size,
                              hipStream_t stream) {
  (void)in_sizes; (void)n_in; (void)out_size;
  const float* v    = (const float*)d_in[0];
  const float* h0   = (const float*)d_in[1];
  const float* Vv   = (const float*)d_in[2];
  const float* Wp   = (const float*)d_in[3];
  const float* Wp_  = (const float*)d_in[4];
  const float* w_ih = (const float*)d_in[5];
  const float* w_hh = (const float*)d_in[6];
  const float* b_ih = (const float*)d_in[7];
  const float* b_hh = (const float*)d_in[8];
  float* out = (float*)d_out;

  // workspace layout; full-tq path needs 126,025,728 B, chunked 81,985,536 B
  const bool full_tq = ws_size >= (size_t)126025728;
  float* ws   = (float*)d_ws;
  float* tk   = ws;                                  // 12,582,912 fl
  float* tqF  = tk + (size_t)12582912;               // full path only
  float* tq_c = tk + (size_t)12582912;               // chunked path only
  float* C_c  = full_tq ? (tqF + (size_t)12582912) : (tq_c + (size_t)1572864);
  float* Gi_c = C_c + (size_t)1572864;               // 4,718,592 fl
  unsigned long long* hb0 = (unsigned long long*)(Gi_c + (size_t)4718592); // 24*512 u64
  unsigned long long* hb1 = hb0 + (size_t)12288;                           // 24*512 u64

  // zero the tagged h buffers once per call (tags are monotone across the
  // 8 GRU launches; replays re-zero via the captured memset)
  hipMemsetAsync(hb0, 0, (size_t)2 * 12288 * sizeof(unsigned long long), stream);

  // key projection (full): tk = tanh(v . Wp_^T)
  gemm_abt_kernel<<<dim3(4, 192), 256, 0, stream>>>(v, Wp_, tk, 512, 512, nullptr, 1);
  if (full_tq)
    gemm_abt_kernel<<<dim3(4, 192), 256, 0, stream>>>(v, Wp, tqF, 512, 512, nullptr, 1);

  for (int c = 0; c < 8; ++c) {
    const float* v_chunk = v + (size_t)c * 128 * 24 * 512;
    const float* tq_use;
    if (full_tq) {
      tq_use = tqF + (size_t)c * 128 * 24 * 512;
    } else {
      gemm_abt_kernel<<<dim3(4, 24), 256, 0, stream>>>(v_chunk, Wp, tq_c, 512, 512, nullptr, 1);
      tq_use = tq_c;
    }
    attn_kernel<<<dim3(32, 24), 256, 0, stream>>>(tq_use, tk, Vv, v, C_c);
    gemm_abt_kernel<<<dim3(12, 24), 256, 0, stream>>>(C_c, w_ih, Gi_c, 512, 1536, b_ih, 0);
    gru_persist_kernel<<<256, 1024, 0, stream>>>(Gi_c, w_hh, b_hh, h0, hb0, hb1,
                                                 out, c * 128);
  }
}

// Round 6
// 10944.405 us; speedup vs baseline: 1.2298x; 1.2298x over previous
//
#include <hip/hip_runtime.h>
#include <math.h>

// L=1024, B=24, D=512.
// Pipeline: tk=tanh(v.Wp_^T) [full]; per 128-i chunk: tq, fused
// scores+softmax+context (attn), Gi = C.w_ih^T+b_ih, then a persistent GRU
// kernel doing 128 steps with tagged-word handshakes.
// R5-R7: compiler never register-pins weights (VGPR 120/128/124/52 vs 192/48
// declared); weights streamed from L2 at ~135 GB/s/CU = the 1.4us/segment
// floor. R8 moved weights to LDS but ALSO fused the 3 batches -> removed the
// stagger -> full cross-block propagation + poll-spin storm exposed per il
// (9.4us/il, FETCH +42MB of L3 poll traffic, VALUBusy 14%).
// R9/R10: combine the two proven halves. LDS-resident weights (32sl x 8grp,
// 16 rows/block, w_lds 108KB) + R5's 3-batch stagger (one batch per segment;
// the other two segments hide publish->consume). Segment body = one 98KB LDS
// weight read ~0.32us -> 3B ~1.1us/il. Prefetch is 2-DEEP (pf0/pf1, issued 2
// segments ~0.9us ahead) so the tag is current on arrival and no spin storm
// forms. R10 resubmit after container flake: s_sleep(2) in the poll (lower
// L3 pressure if a spin forms), gi loads hoisted per-il.
// Skew p(k)=k+4*(k>>5) on w_lds/h_stage keeps b128 reads conflict-free
// (each 8-lane group's 8x16B tiles all 32 banks exactly once).

// ---------------------------------------------------------------------------
// GEMM: out[m][n] = post(A[m][:] . B[n][:] (+ bias[n])), A: MxK rm, B: NxK rm.
__launch_bounds__(256, 2)
__global__ void gemm_abt_kernel(const float* __restrict__ A, const float* __restrict__ B,
                                float* __restrict__ out, int K, int N,
                                const float* __restrict__ bias, int do_tanh) {
  __shared__ __align__(16) float As[16][136];
  __shared__ __align__(16) float Bs[16][136];
  const int m0 = blockIdx.y * 128, n0 = blockIdx.x * 128;
  const int tid = threadIdx.x;
  const int tm = (tid & 15) * 8, tn = (tid >> 4) * 8;
  const int srow = tid & 127, scol = (tid >> 7) * 8;
  const float* Ap = A + (size_t)(m0 + srow) * K + scol;
  const float* Bp = B + (size_t)(n0 + srow) * K + scol;
  float acc[8][8] = {{0.f}};
  for (int k0 = 0; k0 < K; k0 += 16) {
    const float4 a0 = *(const float4*)(Ap + k0);
    const float4 a1 = *(const float4*)(Ap + k0 + 4);
    const float4 b0 = *(const float4*)(Bp + k0);
    const float4 b1 = *(const float4*)(Bp + k0 + 4);
    __syncthreads();
    As[scol + 0][srow] = a0.x; As[scol + 1][srow] = a0.y;
    As[scol + 2][srow] = a0.z; As[scol + 3][srow] = a0.w;
    As[scol + 4][srow] = a1.x; As[scol + 5][srow] = a1.y;
    As[scol + 6][srow] = a1.z; As[scol + 7][srow] = a1.w;
    Bs[scol + 0][srow] = b0.x; Bs[scol + 1][srow] = b0.y;
    Bs[scol + 2][srow] = b0.z; Bs[scol + 3][srow] = b0.w;
    Bs[scol + 4][srow] = b1.x; Bs[scol + 5][srow] = b1.y;
    Bs[scol + 6][srow] = b1.z; Bs[scol + 7][srow] = b1.w;
    __syncthreads();
#pragma unroll
    for (int kk = 0; kk < 16; ++kk) {
      const float4 av0 = *(const float4*)&As[kk][tm];
      const float4 av1 = *(const float4*)&As[kk][tm + 4];
      const float4 bv0 = *(const float4*)&Bs[kk][tn];
      const float4 bv1 = *(const float4*)&Bs[kk][tn + 4];
      const float ar[8] = {av0.x, av0.y, av0.z, av0.w, av1.x, av1.y, av1.z, av1.w};
      const float br[8] = {bv0.x, bv0.y, bv0.z, bv0.w, bv1.x, bv1.y, bv1.z, bv1.w};
#pragma unroll
      for (int r = 0; r < 8; ++r)
#pragma unroll
        for (int c = 0; c < 8; ++c)
          acc[r][c] = fmaf(ar[r], br[c], acc[r][c]);
    }
  }
#pragma unroll
  for (int r = 0; r < 8; ++r) {
    float* o = out + (size_t)(m0 + tm + r) * N + n0 + tn;
#pragma unroll
    for (int c = 0; c < 8; ++c) {
      float val = acc[r][c];
      if (bias) val += bias[n0 + tn + c];
      if (do_tanh) val = tanhf(val);
      o[c] = val;
    }
  }
}

// ---------------------------------------------------------------------------
// Fused scores + softmax + context for one i-chunk.
// tanh(q+k) = u + w(1-u^2)/(1+uw); sum_h V*u is const in l -> dropped
// (softmax-invariant). V'[i][h] = V[h]*(1-u^2) lives in registers.
__launch_bounds__(256, 3)
__global__ void attn_kernel(const float* __restrict__ tq, const float* __restrict__ tk,
                            const float* __restrict__ Vv, const float* __restrict__ v,
                            float* __restrict__ Cout) {
  const int b = blockIdx.y;
  const int it = blockIdx.x;           // i-tile within chunk (il = it*4+ii)
  const int tid = threadIdx.x;
  const int wave = tid >> 6, lane = tid & 63;
  const int h8 = lane * 8;
  __shared__ __align__(16) float sm[4][1024];
  __shared__ __align__(16) float red[4][4][512];
  __shared__ float inv_s[4];

  float q[4][8], vp[4][8];
  {
    const float* vvp = Vv + (size_t)b * 512 + h8;
    const float4 v0 = *(const float4*)vvp;
    const float4 v1 = *(const float4*)(vvp + 4);
    const float vv[8] = {v0.x, v0.y, v0.z, v0.w, v1.x, v1.y, v1.z, v1.w};
#pragma unroll
    for (int ii = 0; ii < 4; ++ii) {
      const float* qp = tq + ((size_t)(it * 4 + ii) * 24 + b) * 512 + h8;
      const float4 q0 = *(const float4*)qp;
      const float4 q1 = *(const float4*)(qp + 4);
      q[ii][0] = q0.x; q[ii][1] = q0.y; q[ii][2] = q0.z; q[ii][3] = q0.w;
      q[ii][4] = q1.x; q[ii][5] = q1.y; q[ii][6] = q1.z; q[ii][7] = q1.w;
#pragma unroll
      for (int j = 0; j < 8; ++j)
        vp[ii][j] = vv[j] * (1.0f - q[ii][j] * q[ii][j]);
    }
  }

  for (int l = wave; l < 1024; l += 4) {
    const float* kp = tk + ((size_t)l * 24 + b) * 512 + h8;
    const float4 k0 = *(const float4*)kp;
    const float4 k1 = *(const float4*)(kp + 4);
    const float kkv[8] = {k0.x, k0.y, k0.z, k0.w, k1.x, k1.y, k1.z, k1.w};
    float acc0 = 0.f, acc1 = 0.f, acc2 = 0.f, acc3 = 0.f;
#pragma unroll
    for (int j = 0; j < 8; ++j) {
      const float w = kkv[j];
      acc0 = fmaf(vp[0][j] * w, __builtin_amdgcn_rcpf(fmaf(q[0][j], w, 1.0f)), acc0);
      acc1 = fmaf(vp[1][j] * w, __builtin_amdgcn_rcpf(fmaf(q[1][j], w, 1.0f)), acc1);
      acc2 = fmaf(vp[2][j] * w, __builtin_amdgcn_rcpf(fmaf(q[2][j], w, 1.0f)), acc2);
      acc3 = fmaf(vp[3][j] * w, __builtin_amdgcn_rcpf(fmaf(q[3][j], w, 1.0f)), acc3);
    }
#pragma unroll
    for (int mask = 32; mask; mask >>= 1) {
      acc0 += __shfl_xor(acc0, mask, 64);
      acc1 += __shfl_xor(acc1, mask, 64);
      acc2 += __shfl_xor(acc2, mask, 64);
      acc3 += __shfl_xor(acc3, mask, 64);
    }
    if (lane == 0) {
      sm[0][l] = acc0; sm[1][l] = acc1; sm[2][l] = acc2; sm[3][l] = acc3;
    }
  }
  __syncthreads();

  // softmax of row `wave` in place (exp only; normalization folded into output)
  {
    float* row = sm[wave];
    float m = -1e30f;
    for (int t = lane; t < 1024; t += 64) m = fmaxf(m, row[t]);
#pragma unroll
    for (int mask = 32; mask; mask >>= 1) m = fmaxf(m, __shfl_xor(m, mask, 64));
    float s = 0.f;
    for (int t = lane; t < 1024; t += 64) {
      const float e = __expf(row[t] - m);
      row[t] = e;
      s += e;
    }
#pragma unroll
    for (int mask = 32; mask; mask >>= 1) s += __shfl_xor(s, mask, 64);
    if (lane == 0) inv_s[wave] = 1.0f / s;
  }
  __syncthreads();

  // context: wave w covers l in [256w, 256w+256), lane owns d-slice h8
  float ca[4][8] = {{0.f}};
  const int l0 = wave * 256;
  for (int l = l0; l < l0 + 256; ++l) {
    const float* vrow = v + ((size_t)l * 24 + b) * 512 + h8;
    const float4 x0 = *(const float4*)vrow;
    const float4 x1 = *(const float4*)(vrow + 4);
    const float a0 = sm[0][l], a1 = sm[1][l], a2 = sm[2][l], a3 = sm[3][l];
    const float xv[8] = {x0.x, x0.y, x0.z, x0.w, x1.x, x1.y, x1.z, x1.w};
#pragma unroll
    for (int j = 0; j < 8; ++j) {
      ca[0][j] = fmaf(a0, xv[j], ca[0][j]);
      ca[1][j] = fmaf(a1, xv[j], ca[1][j]);
      ca[2][j] = fmaf(a2, xv[j], ca[2][j]);
      ca[3][j] = fmaf(a3, xv[j], ca[3][j]);
    }
  }
#pragma unroll
  for (int ii = 0; ii < 4; ++ii) {
    *(float4*)&red[wave][ii][h8]     = make_float4(ca[ii][0], ca[ii][1], ca[ii][2], ca[ii][3]);
    *(float4*)&red[wave][ii][h8 + 4] = make_float4(ca[ii][4], ca[ii][5], ca[ii][6], ca[ii][7]);
  }
  __syncthreads();
  {
    const int ii = tid >> 6;
    const int d0 = (tid & 63) * 8;
    float4 s0 = *(const float4*)&red[0][ii][d0];
    float4 s1 = *(const float4*)&red[0][ii][d0 + 4];
#pragma unroll
    for (int w = 1; w < 4; ++w) {
      const float4 r0 = *(const float4*)&red[w][ii][d0];
      const float4 r1 = *(const float4*)&red[w][ii][d0 + 4];
      s0.x += r0.x; s0.y += r0.y; s0.z += r0.z; s0.w += r0.w;
      s1.x += r1.x; s1.y += r1.y; s1.z += r1.z; s1.w += r1.w;
    }
    const float inv = inv_s[ii];
    s0.x *= inv; s0.y *= inv; s0.z *= inv; s0.w *= inv;
    s1.x *= inv; s1.y *= inv; s1.z *= inv; s1.w *= inv;
    float* o = Cout + ((size_t)(it * 4 + ii) * 24 + b) * 512 + d0;
    *(float4*)o = s0;
    *(float4*)(o + 4) = s1;
  }
}

// ---------------------------------------------------------------------------
// Persistent GRU: LDS-resident weights + 3-batch stagger.
// Grid 256 = 32 d-slices x 8 groups. Block: 1024 thr = 16 waves; wave w owns
// output row dgr = sl*16 + w; lane l owns k-chunk [8l, 8l+8).
// Per il, three SEGMENTS (one batch each): {poll+stage h, barrier, dots from
// w_lds, 6-step shfl butterfly, lane0 gates+publish}. While batch q's
// publish propagates through L3, the block computes the other two batches.
// h exchange: {float h; u32 tag} 8B relaxed agent atomics; consumer at step
// gs polls tag >= gs+1, producer stores tag gs+2; ping-pong hb0/hb1 by step
// parity. Prefetch 2-deep (pf0=next seg, pf1=seg+2) so tags are current on
// arrival. Overwrite-safety and deadlock-freedom by the same induction as
// R5-R7 (sync domain = 32 slice-blocks of a group; segments totally ordered).
union HPack {
  unsigned long long u;
  struct { float f; unsigned tag; } s;
};

__launch_bounds__(1024, 1)
__global__ void gru_persist_kernel(const float* __restrict__ Gi_c,
                                   const float* __restrict__ w_hh,
                                   const float* __restrict__ b_hh,
                                   const float* __restrict__ h0,
                                   unsigned long long* __restrict__ hb0,
                                   unsigned long long* __restrict__ hb1,
                                   float* __restrict__ out, int gstep0) {
  const int g  = blockIdx.x & 7;    // batch group (batches 3g..3g+2, same XCD)
  const int sl = blockIdx.x >> 3;   // d-slice 0..31 (16 rows each)
  const int t  = threadIdx.x;
  const int w  = t >> 6;            // wave == local output row 0..15
  const int l  = t & 63;            // lane == 8-wide k-chunk
  const int dgr = sl * 16 + w;      // global output row

  __shared__ __align__(16) float w_lds[48][576];   // [gate*16+r][p(k)] 108KB
  __shared__ __align__(16) float h_stage[2][576];  // [buf][p(d)]      4.5KB

  // ---- stage w_hh slice into LDS (once per launch) ----
  for (int e = t; e < 24576; e += 1024) {
    const int k = e & 511, gr = e >> 9;      // gr = gate*16 + r
    const int gg = gr >> 4, r = gr & 15;
    w_lds[gr][k + ((k >> 5) << 2)] =
        w_hh[(size_t)(gg * 512 + sl * 16 + r) * 512 + k];
  }
  const float bias_r = b_hh[dgr];
  const float bias_z = b_hh[512 + dgr];
  const float bias_n = b_hh[1024 + dgr];

  // ---- launch 0: seed h0 (own rows only) into hb1 with tag 1 ----
  if (gstep0 == 0 && t < 48) {
    const int q = t >> 4, d = t & 15;
    const int bg = g * 3 + q;
    HPack p; p.s.f = h0[(size_t)bg * 512 + sl * 16 + d]; p.s.tag = 1u;
    __hip_atomic_store(hb1 + (size_t)bg * 512 + sl * 16 + d, p.u,
                       __ATOMIC_RELAXED, __HIP_MEMORY_SCOPE_AGENT);
  }

  float hq[3];   // lane-0-of-wave per-batch previous h (static q indexing)
  HPack pf0, pf1;   // 2-deep prefetch: next segment / segment after
  {
    const unsigned long long* hbR0 = (gstep0 & 1) ? hb0 : hb1;
    if (t < 512) {
      pf0.u = __hip_atomic_load(hbR0 + (size_t)(g * 3 + 0) * 512 + t,
                                __ATOMIC_RELAXED, __HIP_MEMORY_SCOPE_AGENT);
      pf1.u = __hip_atomic_load(hbR0 + (size_t)(g * 3 + 1) * 512 + t,
                                __ATOMIC_RELAXED, __HIP_MEMORY_SCOPE_AGENT);
    }
  }

  for (int il = 0; il < 128; ++il) {
    const int gs = gstep0 + il;
    const unsigned want = (unsigned)(gs + 1);
    const unsigned long long* hbR = (gs & 1) ? hb0 : hb1;
    unsigned long long* hbW = (gs & 1) ? hb1 : hb0;

    // hoist gi loads for all 3 segments of this il (lane 0 of each wave;
    // consumed only after each segment's reduce)
    float gir[3], giz[3], gin[3];
    if (l == 0) {
      const float* gi = Gi_c + ((size_t)il * 24 + g * 3) * 1536 + dgr;
#pragma unroll
      for (int q = 0; q < 3; ++q) {
        gir[q] = gi[q * 1536];
        giz[q] = gi[q * 1536 + 512];
        gin[q] = gi[q * 1536 + 1024];
      }
    }

#pragma unroll
    for (int q = 0; q < 3; ++q) {
      const int bg = g * 3 + q;
      const int buf = (il + q) & 1;   // parity of segment index 3*il+q

      if (t < 512) {
        HPack p = pf0;
        pf0 = pf1;
        // issue prefetch for segment s+2 (~2 segments ahead of its use)
        const unsigned long long* nsrc =
            (q == 0) ? hbR + ((size_t)(g * 3 + 2) * 512 + t)
          : (q == 1) ? hbW + ((size_t)(g * 3 + 0) * 512 + t)   // hbR(gs+1)
                     : hbW + ((size_t)(g * 3 + 1) * 512 + t);
        pf1.u = __hip_atomic_load(nsrc, __ATOMIC_RELAXED, __HIP_MEMORY_SCOPE_AGENT);
        // fast path: prefetched tag already current
        const unsigned long long* src = hbR + (size_t)bg * 512 + t;
        while (p.s.tag < want) {
          p.u = __hip_atomic_load(src, __ATOMIC_RELAXED, __HIP_MEMORY_SCOPE_AGENT);
          if (p.s.tag >= want) break;
          __builtin_amdgcn_s_sleep(2);
        }
        h_stage[buf][t + ((t >> 5) << 2)] = p.s.f;
      }
      __syncthreads();   // the only barrier per segment: h_stage[buf] ready
      if (il == 0 && l == 0) hq[q] = h_stage[buf][dgr + ((dgr >> 5) << 2)];

      // 3 gate-dots for row dgr over k in [8l, 8l+8)
      const int base = (l << 3) + ((l >> 2) << 2);
      const float4 wR0 = *(const float4*)&w_lds[w][base];
      const float4 wR1 = *(const float4*)&w_lds[w][base + 4];
      const float4 wZ0 = *(const float4*)&w_lds[16 + w][base];
      const float4 wZ1 = *(const float4*)&w_lds[16 + w][base + 4];
      const float4 wN0 = *(const float4*)&w_lds[32 + w][base];
      const float4 wN1 = *(const float4*)&w_lds[32 + w][base + 4];
      const float4 hh0 = *(const float4*)&h_stage[buf][base];
      const float4 hh1 = *(const float4*)&h_stage[buf][base + 4];

#define DOT8(W0, W1, X0, X1)                                                  \
  fmaf((W1).w, (X1).w, fmaf((W1).z, (X1).z, fmaf((W1).y, (X1).y,              \
  fmaf((W1).x, (X1).x, fmaf((W0).w, (X0).w, fmaf((W0).z, (X0).z,              \
  fmaf((W0).y, (X0).y, (W0).x * (X0).x)))))))
      float sr = DOT8(wR0, wR1, hh0, hh1);
      float sz = DOT8(wZ0, wZ1, hh0, hh1);
      float sn = DOT8(wN0, wN1, hh0, hh1);
#undef DOT8

      // reduce the 64 k-chunks across the wave (butterfly)
#pragma unroll
      for (int m = 1; m < 64; m <<= 1) {
        sr += __shfl_xor(sr, m, 64);
        sz += __shfl_xor(sz, m, 64);
        sn += __shfl_xor(sn, m, 64);
      }

      if (l == 0) {
        const float rg = __builtin_amdgcn_rcpf(1.0f + __expf(-(gir[q] + sr + bias_r)));
        const float zg = __builtin_amdgcn_rcpf(1.0f + __expf(-(giz[q] + sz + bias_z)));
        const float nx = gin[q] + rg * (sn + bias_n);
        const float e2 = __expf(-2.0f * fabsf(nx));
        const float tn = __builtin_copysignf((1.0f - e2) * __builtin_amdgcn_rcpf(1.0f + e2), nx);
        const float hn = (1.0f - zg) * tn + zg * hq[q];
        hq[q] = hn;
        HPack pw; pw.s.f = hn; pw.s.tag = (unsigned)(gs + 2);
        __hip_atomic_store(hbW + (size_t)bg * 512 + dgr, pw.u,
                           __ATOMIC_RELAXED, __HIP_MEMORY_SCOPE_AGENT);
        out[((size_t)gs * 24 + bg) * 512 + dgr] = hn;   // after publish: off chain
      }
      // no trailing barrier: next segment writes h_stage[buf^1]; WAR against
      // reads from 2 segments ago is ordered by the intervening barrier.
    }
  }
}

// ---------------------------------------------------------------------------
extern "C" void kernel_launch(void* const* d_in, const int* in_sizes, int n_in,
                              void* d_out, int out_size, void* d_ws, size_t ws_size,
                              hipStream_t stream) {
  (void)in_sizes; (void)n_in; (void)out_size;
  const float* v    = (const float*)d_in[0];
  const float* h0   = (const float*)d_in[1];
  const float* Vv   = (const float*)d_in[2];
  const float* Wp   = (const float*)d_in[3];
  const float* Wp_  = (const float*)d_in[4];
  const float* w_ih = (const float*)d_in[5];
  const float* w_hh = (const float*)d_in[6];
  const float* b_ih = (const float*)d_in[7];
  const float* b_hh = (const float*)d_in[8];
  float* out = (float*)d_out;

  // workspace layout; full-tq path needs 126,025,728 B, chunked 81,985,536 B
  const bool full_tq = ws_size >= (size_t)126025728;
  float* ws   = (float*)d_ws;
  float* tk   = ws;                                  // 12,582,912 fl
  float* tqF  = tk + (size_t)12582912;               // full path only
  float* tq_c = tk + (size_t)12582912;               // chunked path only
  float* C_c  = full_tq ? (tqF + (size_t)12582912) : (tq_c + (size_t)1572864);
  float* Gi_c = C_c + (size_t)1572864;               // 4,718,592 fl
  unsigned long long* hb0 = (unsigned long long*)(Gi_c + (size_t)4718592); // 24*512 u64
  unsigned long long* hb1 = hb0 + (size_t)12288;                           // 24*512 u64

  // zero the tagged h buffers once per call (tags are monotone across the
  // 8 GRU launches; replays re-zero via the captured memset)
  hipMemsetAsync(hb0, 0, (size_t)2 * 12288 * sizeof(unsigned long long), stream);

  // key projection (full): tk = tanh(v . Wp_^T)
  gemm_abt_kernel<<<dim3(4, 192), 256, 0, stream>>>(v, Wp_, tk, 512, 512, nullptr, 1);
  if (full_tq)
    gemm_abt_kernel<<<dim3(4, 192), 256, 0, stream>>>(v, Wp, tqF, 512, 512, nullptr, 1);

  for (int c = 0; c < 8; ++c) {
    const float* v_chunk = v + (size_t)c * 128 * 24 * 512;
    const float* tq_use;
    if (full_tq) {
      tq_use = tqF + (size_t)c * 128 * 24 * 512;
    } else {
      gemm_abt_kernel<<<dim3(4, 24), 256, 0, stream>>>(v_chunk, Wp, tq_c, 512, 512, nullptr, 1);
      tq_use = tq_c;
    }
    attn_kernel<<<dim3(32, 24), 256, 0, stream>>>(tq_use, tk, Vv, v, C_c);
    gemm_abt_kernel<<<dim3(12, 24), 256, 0, stream>>>(C_c, w_ih, Gi_c, 512, 1536, b_ih, 0);
    gru_persist_kernel<<<256, 1024, 0, stream>>>(Gi_c, w_hh, b_hh, h0, hb0, hb1,
                                                 out, c * 128);
  }
}

// Round 7
// 9165.026 us; speedup vs baseline: 1.4686x; 1.1941x over previous
//
#include <hip/hip_runtime.h>
#include <math.h>

// L=1024, B=24, D=512.
// Pipeline: tk=tanh(v.Wp_^T) [full]; per 128-i chunk: tq, fused
// scores+softmax+context (attn), Gi = C.w_ih^T+b_ih, then a persistent GRU
// kernel doing 128 steps with tagged-word handshakes.
// R5-R7: compiler never pins PERSISTENT weight arrays (VGPR proof), weights
// stream from L2 at ~291 GB/s/CU (measured R1: 393KB/1.35us) = segment floor.
// R8: fusing all 3 batches exposed propagation + spin storm (9.4us/il).
// R11 post-mortem (R6-numbered run): LDS-resident weights are NOT faster than
// the L2 stream (LDS port 307 GB/s/CU vs measured 291) and shfl masks>=8 are
// LDS-PIPE ops (ds_swizzle/bpermute): 9/wave-seg x 16 waves + full-BW b128
// weight reads serialized ~1.3us/segment on the LDS pipe -> 2.27us segments.
// Conflict ladder: masks<=4 (DPP): 0; <=16: 786K; <=32: 2.5-5e7.
// R12 (this round): PARTIAL FUSION. Groups of 6 batches, sub-segments of 2
// fused batches (transient weight reuse: load w -> 2 FMAs -> dead; compiler
// handles transient regs fine). 128 blocks = 4 groups x 32 slices, 16
// rows/block, 512 thr. Per il: 3 sub-segs x 96KB stream = 288KB (~1.0us);
// cover = 2 sub-segs (~0.8us) + 2-deep prefetch. Reduce: kc 8-wide -> DPP
// masks 1,2,4 ONLY; quarters combined via 480-float LDS bounce (bank-tiled);
// h reads are 8-address broadcasts (skew 20). LDS ~12KB.

// ---------------------------------------------------------------------------
// GEMM: out[m][n] = post(A[m][:] . B[n][:] (+ bias[n])), A: MxK rm, B: NxK rm.
__launch_bounds__(256, 2)
__global__ void gemm_abt_kernel(const float* __restrict__ A, const float* __restrict__ B,
                                float* __restrict__ out, int K, int N,
                                const float* __restrict__ bias, int do_tanh) {
  __shared__ __align__(16) float As[16][136];
  __shared__ __align__(16) float Bs[16][136];
  const int m0 = blockIdx.y * 128, n0 = blockIdx.x * 128;
  const int tid = threadIdx.x;
  const int tm = (tid & 15) * 8, tn = (tid >> 4) * 8;
  const int srow = tid & 127, scol = (tid >> 7) * 8;
  const float* Ap = A + (size_t)(m0 + srow) * K + scol;
  const float* Bp = B + (size_t)(n0 + srow) * K + scol;
  float acc[8][8] = {{0.f}};
  for (int k0 = 0; k0 < K; k0 += 16) {
    const float4 a0 = *(const float4*)(Ap + k0);
    const float4 a1 = *(const float4*)(Ap + k0 + 4);
    const float4 b0 = *(const float4*)(Bp + k0);
    const float4 b1 = *(const float4*)(Bp + k0 + 4);
    __syncthreads();
    As[scol + 0][srow] = a0.x; As[scol + 1][srow] = a0.y;
    As[scol + 2][srow] = a0.z; As[scol + 3][srow] = a0.w;
    As[scol + 4][srow] = a1.x; As[scol + 5][srow] = a1.y;
    As[scol + 6][srow] = a1.z; As[scol + 7][srow] = a1.w;
    Bs[scol + 0][srow] = b0.x; Bs[scol + 1][srow] = b0.y;
    Bs[scol + 2][srow] = b0.z; Bs[scol + 3][srow] = b0.w;
    Bs[scol + 4][srow] = b1.x; Bs[scol + 5][srow] = b1.y;
    Bs[scol + 6][srow] = b1.z; Bs[scol + 7][srow] = b1.w;
    __syncthreads();
#pragma unroll
    for (int kk = 0; kk < 16; ++kk) {
      const float4 av0 = *(const float4*)&As[kk][tm];
      const float4 av1 = *(const float4*)&As[kk][tm + 4];
      const float4 bv0 = *(const float4*)&Bs[kk][tn];
      const float4 bv1 = *(const float4*)&Bs[kk][tn + 4];
      const float ar[8] = {av0.x, av0.y, av0.z, av0.w, av1.x, av1.y, av1.z, av1.w};
      const float br[8] = {bv0.x, bv0.y, bv0.z, bv0.w, bv1.x, bv1.y, bv1.z, bv1.w};
#pragma unroll
      for (int r = 0; r < 8; ++r)
#pragma unroll
        for (int c = 0; c < 8; ++c)
          acc[r][c] = fmaf(ar[r], br[c], acc[r][c]);
    }
  }
#pragma unroll
  for (int r = 0; r < 8; ++r) {
    float* o = out + (size_t)(m0 + tm + r) * N + n0 + tn;
#pragma unroll
    for (int c = 0; c < 8; ++c) {
      float val = acc[r][c];
      if (bias) val += bias[n0 + tn + c];
      if (do_tanh) val = tanhf(val);
      o[c] = val;
    }
  }
}

// ---------------------------------------------------------------------------
// Fused scores + softmax + context for one i-chunk.
// tanh(q+k) = u + w(1-u^2)/(1+uw); sum_h V*u is const in l -> dropped
// (softmax-invariant). V'[i][h] = V[h]*(1-u^2) lives in registers.
__launch_bounds__(256, 3)
__global__ void attn_kernel(const float* __restrict__ tq, const float* __restrict__ tk,
                            const float* __restrict__ Vv, const float* __restrict__ v,
                            float* __restrict__ Cout) {
  const int b = blockIdx.y;
  const int it = blockIdx.x;           // i-tile within chunk (il = it*4+ii)
  const int tid = threadIdx.x;
  const int wave = tid >> 6, lane = tid & 63;
  const int h8 = lane * 8;
  __shared__ __align__(16) float sm[4][1024];
  __shared__ __align__(16) float red[4][4][512];
  __shared__ float inv_s[4];

  float q[4][8], vp[4][8];
  {
    const float* vvp = Vv + (size_t)b * 512 + h8;
    const float4 v0 = *(const float4*)vvp;
    const float4 v1 = *(const float4*)(vvp + 4);
    const float vv[8] = {v0.x, v0.y, v0.z, v0.w, v1.x, v1.y, v1.z, v1.w};
#pragma unroll
    for (int ii = 0; ii < 4; ++ii) {
      const float* qp = tq + ((size_t)(it * 4 + ii) * 24 + b) * 512 + h8;
      const float4 q0 = *(const float4*)qp;
      const float4 q1 = *(const float4*)(qp + 4);
      q[ii][0] = q0.x; q[ii][1] = q0.y; q[ii][2] = q0.z; q[ii][3] = q0.w;
      q[ii][4] = q1.x; q[ii][5] = q1.y; q[ii][6] = q1.z; q[ii][7] = q1.w;
#pragma unroll
      for (int j = 0; j < 8; ++j)
        vp[ii][j] = vv[j] * (1.0f - q[ii][j] * q[ii][j]);
    }
  }

  for (int l = wave; l < 1024; l += 4) {
    const float* kp = tk + ((size_t)l * 24 + b) * 512 + h8;
    const float4 k0 = *(const float4*)kp;
    const float4 k1 = *(const float4*)(kp + 4);
    const float kkv[8] = {k0.x, k0.y, k0.z, k0.w, k1.x, k1.y, k1.z, k1.w};
    float acc0 = 0.f, acc1 = 0.f, acc2 = 0.f, acc3 = 0.f;
#pragma unroll
    for (int j = 0; j < 8; ++j) {
      const float w = kkv[j];
      acc0 = fmaf(vp[0][j] * w, __builtin_amdgcn_rcpf(fmaf(q[0][j], w, 1.0f)), acc0);
      acc1 = fmaf(vp[1][j] * w, __builtin_amdgcn_rcpf(fmaf(q[1][j], w, 1.0f)), acc1);
      acc2 = fmaf(vp[2][j] * w, __builtin_amdgcn_rcpf(fmaf(q[2][j], w, 1.0f)), acc2);
      acc3 = fmaf(vp[3][j] * w, __builtin_amdgcn_rcpf(fmaf(q[3][j], w, 1.0f)), acc3);
    }
#pragma unroll
    for (int mask = 32; mask; mask >>= 1) {
      acc0 += __shfl_xor(acc0, mask, 64);
      acc1 += __shfl_xor(acc1, mask, 64);
      acc2 += __shfl_xor(acc2, mask, 64);
      acc3 += __shfl_xor(acc3, mask, 64);
    }
    if (lane == 0) {
      sm[0][l] = acc0; sm[1][l] = acc1; sm[2][l] = acc2; sm[3][l] = acc3;
    }
  }
  __syncthreads();

  // softmax of row `wave` in place (exp only; normalization folded into output)
  {
    float* row = sm[wave];
    float m = -1e30f;
    for (int t = lane; t < 1024; t += 64) m = fmaxf(m, row[t]);
#pragma unroll
    for (int mask = 32; mask; mask >>= 1) m = fmaxf(m, __shfl_xor(m, mask, 64));
    float s = 0.f;
    for (int t = lane; t < 1024; t += 64) {
      const float e = __expf(row[t] - m);
      row[t] = e;
      s += e;
    }
#pragma unroll
    for (int mask = 32; mask; mask >>= 1) s += __shfl_xor(s, mask, 64);
    if (lane == 0) inv_s[wave] = 1.0f / s;
  }
  __syncthreads();

  // context: wave w covers l in [256w, 256w+256), lane owns d-slice h8
  float ca[4][8] = {{0.f}};
  const int l0 = wave * 256;
  for (int l = l0; l < l0 + 256; ++l) {
    const float* vrow = v + ((size_t)l * 24 + b) * 512 + h8;
    const float4 x0 = *(const float4*)vrow;
    const float4 x1 = *(const float4*)(vrow + 4);
    const float a0 = sm[0][l], a1 = sm[1][l], a2 = sm[2][l], a3 = sm[3][l];
    const float xv[8] = {x0.x, x0.y, x0.z, x0.w, x1.x, x1.y, x1.z, x1.w};
#pragma unroll
    for (int j = 0; j < 8; ++j) {
      ca[0][j] = fmaf(a0, xv[j], ca[0][j]);
      ca[1][j] = fmaf(a1, xv[j], ca[1][j]);
      ca[2][j] = fmaf(a2, xv[j], ca[2][j]);
      ca[3][j] = fmaf(a3, xv[j], ca[3][j]);
    }
  }
#pragma unroll
  for (int ii = 0; ii < 4; ++ii) {
    *(float4*)&red[wave][ii][h8]     = make_float4(ca[ii][0], ca[ii][1], ca[ii][2], ca[ii][3]);
    *(float4*)&red[wave][ii][h8 + 4] = make_float4(ca[ii][4], ca[ii][5], ca[ii][6], ca[ii][7]);
  }
  __syncthreads();
  {
    const int ii = tid >> 6;
    const int d0 = (tid & 63) * 8;
    float4 s0 = *(const float4*)&red[0][ii][d0];
    float4 s1 = *(const float4*)&red[0][ii][d0 + 4];
#pragma unroll
    for (int w = 1; w < 4; ++w) {
      const float4 r0 = *(const float4*)&red[w][ii][d0];
      const float4 r1 = *(const float4*)&red[w][ii][d0 + 4];
      s0.x += r0.x; s0.y += r0.y; s0.z += r0.z; s0.w += r0.w;
      s1.x += r1.x; s1.y += r1.y; s1.z += r1.z; s1.w += r1.w;
    }
    const float inv = inv_s[ii];
    s0.x *= inv; s0.y *= inv; s0.z *= inv; s0.w *= inv;
    s1.x *= inv; s1.y *= inv; s1.z *= inv; s1.w *= inv;
    float* o = Cout + ((size_t)(it * 4 + ii) * 24 + b) * 512 + d0;
    *(float4*)o = s0;
    *(float4*)(o + 4) = s1;
  }
}

// ---------------------------------------------------------------------------
// Persistent GRU: L2-streamed weights with 2-batch fusion, 6-batch stagger.
// Grid 128 = 4 groups x 32 slices. Block: 512 thr = 8 waves, 16 output rows.
// Thread (w, og=l>>3, kc=l&7): row = 8*(w&1)+og, k-quarter = w>>1,
// k-chunk = quarter*128 + kc*16 .. +16. Per il: 3 sub-segments, each fusing
// batches (2s, 2s+1): one transient weight load serves 2 FMAs (compiler
// keeps transient regs; only PERSISTENT arrays get demoted, R5-R7).
// Reduce: masks 1,2,4 DPP only (zero LDS-pipe); the 4 k-quarters combine
// via a 480-float bank-tiled LDS bounce (red). h reads are 8-address
// broadcasts (chunk stride 20 -> banks tiled). 2 barriers/sub-segment.
// h exchange: {float h; u32 tag} 8B relaxed agent atomics; consumer at step
// gs polls tag >= gs+1, producer stores tag gs+2; ping-pong hb0/hb1 by step
// parity. 2-deep prefetch (pf*0/pf*1, lead = 2 sub-segments ~0.9us).
// Overwrite-safety/deadlock-freedom: same induction as R5-R7 (sub-segments
// totally ordered; every consume precedes the same block's publish).
union HPack {
  unsigned long long u;
  struct { float f; unsigned tag; } s;
};

__launch_bounds__(512, 1)
__global__ void gru_persist_kernel(const float* __restrict__ Gi_c,
                                   const float* __restrict__ w_hh,
                                   const float* __restrict__ b_hh,
                                   const float* __restrict__ h0,
                                   unsigned long long* __restrict__ hb0,
                                   unsigned long long* __restrict__ hb1,
                                   float* __restrict__ out, int gstep0) {
  const int g  = blockIdx.x & 3;    // batch group: batches 6g..6g+5
  const int sl = blockIdx.x >> 2;   // d-slice 0..31 (16 rows each)
  const int t  = threadIdx.x;       // 512
  const int w  = t >> 6;            // wave 0..7
  const int l  = t & 63;
  const int og = l >> 3;            // 0..7
  const int kc = l & 7;             // 0..7 (16-float chunk)
  const int row = ((w & 1) << 3) + og;   // local row 0..15
  const int quarter = w >> 1;            // k-quarter 0..3
  const int dgr = sl * 16 + row;         // global output row

  // h staging: element d at [buf][ab][(d>>4)*20 + (d&15)] -> 8 bcast addrs
  // per wave read tile banks {0,20,8,28,16,4,24,12}+0..3 (conflict-free).
  __shared__ __align__(16) float h_lds[2][2][640];
  // quarter-partials: [ab][gate][row][quarter pad->5]; og-write stride 20
  // banks tiled; single live buffer (WAR split by next sub-seg's bar1).
  __shared__ float red[2][3][16][5];

  // ---- launch 0: seed h0 (own rows) into hb1 with tag 1 ----
  if (gstep0 == 0 && t < 96) {
    const int q = t >> 4, d = t & 15;
    const int bg = g * 6 + q;
    HPack p; p.s.f = h0[(size_t)bg * 512 + sl * 16 + d]; p.s.tag = 1u;
    __hip_atomic_store(hb1 + (size_t)bg * 512 + sl * 16 + d, p.u,
                       __ATOMIC_RELAXED, __HIP_MEMORY_SCOPE_AGENT);
  }

  // pub threads: t<32 -> (prow = t>>1, pb = t&1) handles batch 2s+pb, row prow
  const int prow = t >> 1, pb = t & 1;
  const int pdgr = sl * 16 + prow;
  float pbias_r = 0.f, pbias_z = 0.f, pbias_n = 0.f;
  if (t < 32) {
    pbias_r = b_hh[pdgr]; pbias_z = b_hh[512 + pdgr]; pbias_n = b_hh[1024 + pdgr];
  }

  // transient per-thread weight base pointers (stream from L2 each sub-seg)
  const float* wr_p = w_hh + ((size_t)dgr          << 9) + quarter * 128 + kc * 16;
  const float* wz_p = w_hh + ((size_t)(512 + dgr)  << 9) + quarter * 128 + kc * 16;
  const float* wn_p = w_hh + ((size_t)(1024 + dgr) << 9) + quarter * 128 + kc * 16;

  float hq[3];   // pub-thread previous h per sub-segment slot (static idx)

  // 2-deep prefetch: pf*0 = next sub-seg, pf*1 = the one after
  HPack pfA0, pfB0, pfA1, pfB1;
  {
    const unsigned long long* hbR0 = (gstep0 & 1) ? hb0 : hb1;
    pfA0.u = __hip_atomic_load(hbR0 + (size_t)(g * 6 + 0) * 512 + t,
                               __ATOMIC_RELAXED, __HIP_MEMORY_SCOPE_AGENT);
    pfB0.u = __hip_atomic_load(hbR0 + (size_t)(g * 6 + 1) * 512 + t,
                               __ATOMIC_RELAXED, __HIP_MEMORY_SCOPE_AGENT);
    pfA1.u = __hip_atomic_load(hbR0 + (size_t)(g * 6 + 2) * 512 + t,
                               __ATOMIC_RELAXED, __HIP_MEMORY_SCOPE_AGENT);
    pfB1.u = __hip_atomic_load(hbR0 + (size_t)(g * 6 + 3) * 512 + t,
                               __ATOMIC_RELAXED, __HIP_MEMORY_SCOPE_AGENT);
  }

  for (int il = 0; il < 128; ++il) {
    const int gs = gstep0 + il;
    const unsigned want = (unsigned)(gs + 1);
    const unsigned long long* hbR = (gs & 1) ? hb0 : hb1;
    unsigned long long* hbW = (gs & 1) ? hb1 : hb0;

#pragma unroll
    for (int s = 0; s < 3; ++s) {
      const int bgA = g * 6 + 2 * s;
      const int buf = (il + s) & 1;

      // gi loads (pub threads; independent of h -> overlap the poll)
      float gir = 0.f, giz = 0.f, gin = 0.f;
      if (t < 32) {
        const float* gi = Gi_c + ((size_t)il * 24 + bgA + pb) * 1536 + pdgr;
        gir = gi[0]; giz = gi[512]; gin = gi[1024];
      }

      // consume prefetched words; rotate; prefetch sub-seg +2
      HPack pA = pfA0, pB = pfB0;
      pfA0 = pfA1; pfB0 = pfB1;
      {
        const int ns  = (s + 2) % 3;            // sub-seg (il,s)+2
        const int ngs = gs + (s >= 1 ? 1 : 0);
        const unsigned long long* hbR2 = (ngs & 1) ? hb0 : hb1;
        pfA1.u = __hip_atomic_load(hbR2 + (size_t)(g * 6 + 2 * ns) * 512 + t,
                                   __ATOMIC_RELAXED, __HIP_MEMORY_SCOPE_AGENT);
        pfB1.u = __hip_atomic_load(hbR2 + (size_t)(g * 6 + 2 * ns + 1) * 512 + t,
                                   __ATOMIC_RELAXED, __HIP_MEMORY_SCOPE_AGENT);
      }
      const unsigned long long* srcA = hbR + (size_t)bgA * 512 + t;
      const unsigned long long* srcB = srcA + 512;
      while (pA.s.tag < want) {
        pA.u = __hip_atomic_load(srcA, __ATOMIC_RELAXED, __HIP_MEMORY_SCOPE_AGENT);
        if (pA.s.tag >= want) break;
        __builtin_amdgcn_s_sleep(2);
      }
      while (pB.s.tag < want) {
        pB.u = __hip_atomic_load(srcB, __ATOMIC_RELAXED, __HIP_MEMORY_SCOPE_AGENT);
        if (pB.s.tag >= want) break;
        __builtin_amdgcn_s_sleep(2);
      }
      const int sk = ((t >> 4) * 20) + (t & 15);
      h_lds[buf][0][sk] = pA.s.f;
      h_lds[buf][1][sk] = pB.s.f;
      __syncthreads();   // bar1: h_lds[buf] ready
      if (il == 0 && t < 32)
        hq[s] = h_lds[buf][pb][((pdgr & 511) >> 4) * 20 + (pdgr & 15)];

      // 6 dots (3 gates x 2 batches) over k in [quarter*128+kc*16, +16)
      const float* hA = &h_lds[buf][0][(quarter * 8 + kc) * 20];
      const float* hB = &h_lds[buf][1][(quarter * 8 + kc) * 20];
      float sAr = 0.f, sAz = 0.f, sAn = 0.f, sBr = 0.f, sBz = 0.f, sBn = 0.f;
#pragma unroll
      for (int j = 0; j < 16; j += 4) {
        const float4 wr = *(const float4*)(wr_p + j);
        const float4 wz = *(const float4*)(wz_p + j);
        const float4 wn = *(const float4*)(wn_p + j);
        const float4 ha = *(const float4*)(hA + j);
        const float4 hb = *(const float4*)(hB + j);
        sAr = fmaf(wr.x, ha.x, fmaf(wr.y, ha.y, fmaf(wr.z, ha.z, fmaf(wr.w, ha.w, sAr))));
        sBr = fmaf(wr.x, hb.x, fmaf(wr.y, hb.y, fmaf(wr.z, hb.z, fmaf(wr.w, hb.w, sBr))));
        sAz = fmaf(wz.x, ha.x, fmaf(wz.y, ha.y, fmaf(wz.z, ha.z, fmaf(wz.w, ha.w, sAz))));
        sBz = fmaf(wz.x, hb.x, fmaf(wz.y, hb.y, fmaf(wz.z, hb.z, fmaf(wz.w, hb.w, sBz))));
        sAn = fmaf(wn.x, ha.x, fmaf(wn.y, ha.y, fmaf(wn.z, ha.z, fmaf(wn.w, ha.w, sAn))));
        sBn = fmaf(wn.x, hb.x, fmaf(wn.y, hb.y, fmaf(wn.z, hb.z, fmaf(wn.w, hb.w, sBn))));
      }
      // DPP-only reduce over kc (masks 1,2,4 stay within the 8-lane group)
#pragma unroll
      for (int m = 1; m <= 4; m <<= 1) {
        sAr += __shfl_xor(sAr, m, 64);
        sAz += __shfl_xor(sAz, m, 64);
        sAn += __shfl_xor(sAn, m, 64);
        sBr += __shfl_xor(sBr, m, 64);
        sBz += __shfl_xor(sBz, m, 64);
        sBn += __shfl_xor(sBn, m, 64);
      }
      if (kc == 0) {   // one lane per (row, quarter): quarter-partials
        red[0][0][row][quarter] = sAr;
        red[0][1][row][quarter] = sAz;
        red[0][2][row][quarter] = sAn;
        red[1][0][row][quarter] = sBr;
        red[1][1][row][quarter] = sBz;
        red[1][2][row][quarter] = sBn;
      }
      __syncthreads();   // bar2: partials ready

      if (t < 32) {
        const float* r0 = red[pb][0][prow];
        const float* r1 = red[pb][1][prow];
        const float* r2 = red[pb][2][prow];
        const float sr = (r0[0] + r0[1]) + (r0[2] + r0[3]);
        const float sz = (r1[0] + r1[1]) + (r1[2] + r1[3]);
        const float sn = (r2[0] + r2[1]) + (r2[2] + r2[3]);
        const float rg = __builtin_amdgcn_rcpf(1.0f + __expf(-(gir + sr + pbias_r)));
        const float zg = __builtin_amdgcn_rcpf(1.0f + __expf(-(giz + sz + pbias_z)));
        const float nx = gin + rg * (sn + pbias_n);
        const float e2 = __expf(-2.0f * fabsf(nx));
        const float tn = __builtin_copysignf((1.0f - e2) * __builtin_amdgcn_rcpf(1.0f + e2), nx);
        const float hn = (1.0f - zg) * tn + zg * hq[s];
        hq[s] = hn;
        HPack pw; pw.s.f = hn; pw.s.tag = (unsigned)(gs + 2);
        __hip_atomic_store(hbW + (size_t)(bgA + pb) * 512 + pdgr, pw.u,
                           __ATOMIC_RELAXED, __HIP_MEMORY_SCOPE_AGENT);
        out[((size_t)gs * 24 + bgA + pb) * 512 + pdgr] = hn;   // off chain
      }
      // no trailing barrier: next sub-seg stages into h_lds[buf^1]; h WAR is
      // split by the 2 intervening barriers; red WAR by the next bar1.
    }
  }
}

// ---------------------------------------------------------------------------
extern "C" void kernel_launch(void* const* d_in, const int* in_sizes, int n_in,
                              void* d_out, int out_size, void* d_ws, size_t ws_size,
                              hipStream_t stream) {
  (void)in_sizes; (void)n_in; (void)out_size;
  const float* v    = (const float*)d_in[0];
  const float* h0   = (const float*)d_in[1];
  const float* Vv   = (const float*)d_in[2];
  const float* Wp   = (const float*)d_in[3];
  const float* Wp_  = (const float*)d_in[4];
  const float* w_ih = (const float*)d_in[5];
  const float* w_hh = (const float*)d_in[6];
  const float* b_ih = (const float*)d_in[7];
  const float* b_hh = (const float*)d_in[8];
  float* out = (float*)d_out;

  // workspace layout; full-tq path needs 126,025,728 B, chunked 81,985,536 B
  const bool full_tq = ws_size >= (size_t)126025728;
  float* ws   = (float*)d_ws;
  float* tk   = ws;                                  // 12,582,912 fl
  float* tqF  = tk + (size_t)12582912;               // full path only
  float* tq_c = tk + (size_t)12582912;               // chunked path only
  float* C_c  = full_tq ? (tqF + (size_t)12582912) : (tq_c + (size_t)1572864);
  float* Gi_c = C_c + (size_t)1572864;               // 4,718,592 fl
  unsigned long long* hb0 = (unsigned long long*)(Gi_c + (size_t)4718592); // 24*512 u64
  unsigned long long* hb1 = hb0 + (size_t)12288;                           // 24*512 u64

  // zero the tagged h buffers once per call (tags are monotone across the
  // 8 GRU launches; replays re-zero via the captured memset)
  hipMemsetAsync(hb0, 0, (size_t)2 * 12288 * sizeof(unsigned long long), stream);

  // key projection (full): tk = tanh(v . Wp_^T)
  gemm_abt_kernel<<<dim3(4, 192), 256, 0, stream>>>(v, Wp_, tk, 512, 512, nullptr, 1);
  if (full_tq)
    gemm_abt_kernel<<<dim3(4, 192), 256, 0, stream>>>(v, Wp, tqF, 512, 512, nullptr, 1);

  for (int c = 0; c < 8; ++c) {
    const float* v_chunk = v + (size_t)c * 128 * 24 * 512;
    const float* tq_use;
    if (full_tq) {
      tq_use = tqF + (size_t)c * 128 * 24 * 512;
    } else {
      gemm_abt_kernel<<<dim3(4, 24), 256, 0, stream>>>(v_chunk, Wp, tq_c, 512, 512, nullptr, 1);
      tq_use = tq_c;
    }
    attn_kernel<<<dim3(32, 24), 256, 0, stream>>>(tq_use, tk, Vv, v, C_c);
    gemm_abt_kernel<<<dim3(12, 24), 256, 0, stream>>>(C_c, w_ih, Gi_c, 512, 1536, b_ih, 0);
    gru_persist_kernel<<<128, 512, 0, stream>>>(Gi_c, w_hh, b_hh, h0, hb0, hb1,
                                                out, c * 128);
  }
}